// Round 15
// baseline (492.715 us; speedup 1.0000x reference)
//
#include <hip/hip_runtime.h>
#include <hip/hip_bf16.h>

#define Bn  512
#define Sn  30
#define Dm  300
#define Hn  20
#define DHn 20
#define AHn 200
#define HDn 400
#define EQn 6000
#define KP  320           // GEMM K padded to 10*32
#define NW  6400          // N = 6000 (Wq) + 400 (Wv) = 50*128 exactly
#define KB  328           // qb/kb LDS row stride (bf16)
#define CFS 304           // cf LDS row stride (bf16)

typedef __attribute__((ext_vector_type(8))) short short8;
typedef __attribute__((ext_vector_type(4))) short short4v;
typedef __attribute__((ext_vector_type(4))) float f32x4;

__device__ __forceinline__ unsigned short f2b(float v) {
    __hip_bfloat16 h = __float2bfloat16(v);
    return *(unsigned short*)&h;
}
__device__ __forceinline__ float b2f(unsigned short u) {
    union { unsigned int i; float f; } cv; cv.i = ((unsigned int)u) << 16; return cv.f;
}

// ---------------------------------------------------------------------------
// k_c: cbf[(bl*30+s)*320 + d] = bf16(emb[x][d] + PE(s,d)), K-pad zeroed
// ---------------------------------------------------------------------------
__global__ __launch_bounds__(256) void k_c(const int* __restrict__ x,
        const float* __restrict__ emb, unsigned short* __restrict__ cbf,
        int b0, int nloc)
{
    int n = nloc * Sn * Dm;
    for (int p = blockIdx.x * 256 + threadIdx.x; p < n; p += gridDim.x * 256) {
        int bl = p / (Sn * Dm);
        int r  = p - bl * (Sn * Dm);
        int s = r / Dm, d = r - s * Dm;
        int tok = x[(b0 + bl) * Sn + s];
        float dv = expf(-0.06140226914650789f * (float)(d >> 1));
        float ang = (float)s * dv;
        float val = emb[(size_t)tok * Dm + d] + ((d & 1) ? cosf(ang) : sinf(ang));
        cbf[(size_t)(bl * Sn + s) * KP + d] = f2b(val);
    }
    int npad = nloc * Sn * (KP - Dm);
    for (int p = blockIdx.x * 256 + threadIdx.x; p < npad; p += gridDim.x * 256) {
        int m = p / (KP - Dm), k = Dm + p % (KP - Dm);
        cbf[(size_t)m * KP + k] = 0;
    }
}

// ---------------------------------------------------------------------------
// k_cast_w: Wb[NW][KP] = bf16([Wq; Wv]) zero-padded    (once per launch)
// ---------------------------------------------------------------------------
__global__ __launch_bounds__(256) void k_cast_w(const float* __restrict__ Wq,
        const float* __restrict__ Wv, unsigned short* __restrict__ Wb)
{
    for (int p = blockIdx.x * 256 + threadIdx.x; p < NW * KP; p += gridDim.x * 256) {
        int nq = p / KP, k = p - nq * KP;
        float v = 0.f;
        if (k < Dm)
            v = (nq < EQn) ? Wq[(size_t)nq * Dm + k]
                           : Wv[(size_t)(nq - EQn) * Dm + k];
        Wb[p] = f2b(v);
    }
}

// ---------------------------------------------------------------------------
// k_xqm: [xqb | xvb][m][n] = bf16(sum_k cbf[m][k]*Wb[n][k] + bias)
// (verified R14 kernel, unchanged)
// ---------------------------------------------------------------------------
__global__ __launch_bounds__(256) void k_xqm(const unsigned short* __restrict__ Ab,
        const unsigned short* __restrict__ Bb, const float* __restrict__ bq,
        const float* __restrict__ bv, unsigned short* __restrict__ xqb,
        unsigned short* __restrict__ xvb, int Mloc, int mtiles)
{
    __shared__ __attribute__((aligned(16))) char smem[36864];
    unsigned short (*As)[72] = (unsigned short (*)[72])smem;
    unsigned short (*Bs)[72] = (unsigned short (*)[72])(smem + 18432);
    unsigned short (*Cs)[136] = (unsigned short (*)[136])smem;

    int nwg = 50 * mtiles;
    int bid = blockIdx.x;
    int q8 = nwg >> 3, r8 = nwg & 7;
    int xcd = bid & 7, idx = bid >> 3;
    int wg = (xcd < r8 ? xcd * (q8 + 1) : r8 * (q8 + 1) + (xcd - r8) * q8) + idx;
    int bx = wg % 50, by = wg / 50;

    int t = threadIdx.x;
    int l = t & 63, w = t >> 6;
    int wm = w >> 1, wn = w & 1;
    int m0 = by * 128, n0 = bx * 128;
    int cl = l & 15, rh = l >> 4;

    f32x4 zero4 = {0.f, 0.f, 0.f, 0.f};
    f32x4 acc[4][4];
    #pragma unroll
    for (int a = 0; a < 4; ++a)
        #pragma unroll
        for (int bb = 0; bb < 4; ++bb) acc[a][bb] = zero4;

    for (int k0 = 0; k0 < KP; k0 += 64) {
        #pragma unroll
        for (int cc = 0; cc < 4; ++cc) {
            int qq = t + 256 * cc;
            int row = qq >> 3, kc = (qq & 7) * 8;
            int gm = m0 + row;
            short8 av = {0, 0, 0, 0, 0, 0, 0, 0};
            if (gm < Mloc) av = *(const short8*)&Ab[(size_t)gm * KP + k0 + kc];
            *(short8*)&As[row][kc] = av;
            short8 bvv = *(const short8*)&Bb[(size_t)(n0 + row) * KP + k0 + kc];
            *(short8*)&Bs[row][kc] = bvv;
        }
        __syncthreads();
        #pragma unroll
        for (int k2 = 0; k2 < 2; ++k2) {
            int kk = k2 * 32 + rh * 8;
            short8 af[4], bf[4];
            #pragma unroll
            for (int f = 0; f < 4; ++f) {
                af[f] = *(const short8*)&As[wm * 64 + f * 16 + cl][kk];
                bf[f] = *(const short8*)&Bs[wn * 64 + f * 16 + cl][kk];
            }
            #pragma unroll
            for (int mf = 0; mf < 4; ++mf)
                #pragma unroll
                for (int nf = 0; nf < 4; ++nf)
                    acc[mf][nf] = __builtin_amdgcn_mfma_f32_16x16x32_bf16(
                        af[mf], bf[nf], acc[mf][nf], 0, 0, 0);
        }
        __syncthreads();
    }

    #pragma unroll
    for (int nf = 0; nf < 4; ++nf) {
        int gn = n0 + wn * 64 + nf * 16 + cl;
        float bias = (gn < EQn) ? bq[gn] : bv[gn - EQn];
        #pragma unroll
        for (int mf = 0; mf < 4; ++mf) {
            int lrow = wm * 64 + mf * 16 + rh * 4;
            #pragma unroll
            for (int r = 0; r < 4; ++r)
                Cs[lrow + r][wn * 64 + nf * 16 + cl] = f2b(acc[mf][nf][r] + bias);
        }
    }
    __syncthreads();

    for (int ch = t; ch < 128 * 16; ch += 256) {
        int row = ch >> 4, colc = (ch & 15) * 8;
        int gm = m0 + row;
        if (gm >= Mloc) continue;
        short8 v = *(const short8*)&Cs[row][colc];
        int gn = n0 + colc;
        if (gn < EQn) *(short8*)&xqb[(size_t)gm * EQn + gn] = v;
        else          *(short8*)&xvb[(size_t)gm * HDn + (gn - EQn)] = v;
    }
}

// ---------------------------------------------------------------------------
// k_attn v3: ONE BLOCK PER bl (4 waves). K transposed once; 20-head loop;
// MFMA scores; axis=-2 softmax; PV; FUSED additive pooling -> out.
// LDS plan (byte offsets, aligned 16):
//   [0,20992)      kb   bf16 [32][328]
//   [20992,41984)  qb   bf16 [32][328]
//   [41984,89984)  h2b  f32  [12000]   (first 18240 B alias cf bf16 [30][304])
//   [89984,94208)  wm   f32  [32][33]
//   [94208,96608)  vm   f32  [600]
//   [96608,...]    part/colv/wpart/psm
// ---------------------------------------------------------------------------
__global__ __launch_bounds__(256) void k_attn(const unsigned short* __restrict__ cbf,
        const unsigned short* __restrict__ xqb, const unsigned short* __restrict__ xvb,
        const float* __restrict__ WVm, const float* __restrict__ bV,
        const float* __restrict__ wq2, const float* __restrict__ bq2,
        float* __restrict__ out, int b0)
{
    __shared__ __attribute__((aligned(16))) char smem[98288];
    unsigned short* kb  = (unsigned short*)(smem);
    unsigned short* qb  = (unsigned short*)(smem + 20992);
    float*          h2b = (float*)(smem + 41984);
    unsigned short* cf  = (unsigned short*)(smem + 41984);
    float*          wm_s = (float*)(smem + 89984);
    float*          vm  = (float*)(smem + 94208);
    float*          part = (float*)(smem + 96608);
    float*          colv = (float*)(smem + 97568);
    float*          wpart = (float*)(smem + 97688);   // [4][30]
    float*          psm  = (float*)(smem + 98168);

    int bl = blockIdx.x, t = threadIdx.x;
    int l = t & 63, w = t >> 6;
    int cl = l & 15, rh = l >> 4;

    // zero pads of qb/kb: cols 300..319 rows 0..29, and rows 30..31 whole
    for (int p = t; p < 600; p += 256) {
        int r = p / 20, cc = Dm + p % 20;
        qb[r * KB + cc] = 0; kb[r * KB + cc] = 0;
    }
    for (int p = t; p < 2 * KB; p += 256) {
        qb[30 * KB + p] = 0; kb[30 * KB + p] = 0;
    }

    // stage cf = cbf[bl] rows (30 x 300 of stride-320 rows), short8 chunks
    for (int q = t; q < 30 * 38; q += 256) {
        int i = q / 38, cc = q % 38, d0 = cc * 8;
        const unsigned short* src = &cbf[(size_t)(bl * Sn + i) * KP + d0];
        if (d0 + 8 <= Dm) *(short8*)&cf[i * CFS + d0] = *(const short8*)src;
        else              *(short4v*)&cf[i * CFS + d0] = *(const short4v*)src; // tail 4
    }
    __syncthreads();

    // transpose: kb[j][d] = K(d,j) = c_flat[d*30+j];  c_flat[f] = cf[(f/300)*CFS + f%300]
    for (int p = t; p < Sn * Dm; p += 256) {
        int j = p / Dm, d = p - j * Dm;
        int f = d * Sn + j;
        kb[j * KB + d] = cf[(f / Dm) * CFS + (f % Dm)];
    }
    __syncthreads();   // cf dead; h2b region free

    for (int h = 0; h < Hn; ++h) {
        // ---- stage Q (head slice = 9000 contiguous bf16) + V ----
        const unsigned short* qsrc = xqb + (size_t)bl * (Sn * EQn) + (size_t)h * (Sn * Dm);
        for (int q = t; q < 30 * 38; q += 256) {
            int i = q / 38, cc = q % 38, d0 = cc * 8;
            const unsigned short* src = &qsrc[i * Dm + d0];
            if (d0 + 8 <= Dm) *(short8*)&qb[i * KB + d0] = *(const short8*)src;
            else              *(short4v*)&qb[i * KB + d0] = *(const short4v*)src;
        }
        if (t < 75) {
            short8 v = *(const short8*)&xvb[(size_t)bl * (Sn * HDn) + h * (Sn * DHn) + t * 8];
            #pragma unroll
            for (int e = 0; e < 8; ++e) vm[t * 8 + e] = b2f((unsigned short)v[e]);
        }
        __syncthreads();

        // ---- scores via MFMA: wave w -> 16x16 tile (w>>1, w&1) ----
        {
            int wmt = w >> 1, wnt = w & 1;
            f32x4 acc = {0.f, 0.f, 0.f, 0.f};
            #pragma unroll
            for (int ks = 0; ks < 10; ++ks) {
                short8 a = *(const short8*)&qb[(wmt * 16 + cl) * KB + ks * 32 + rh * 8];
                short8 b = *(const short8*)&kb[(wnt * 16 + cl) * KB + ks * 32 + rh * 8];
                acc = __builtin_amdgcn_mfma_f32_16x16x32_bf16(a, b, acc, 0, 0, 0);
            }
            #pragma unroll
            for (int r = 0; r < 4; ++r) {
                int i = wmt * 16 + rh * 4 + r, j = wnt * 16 + cl;
                if (i < Sn && j < Sn) wm_s[i * 33 + j] = acc[r];
            }
        }
        __syncthreads();

        // ---- softmax over query dim i (per column j) ----
        if (t < 240) {
            int j = t % 30, r = t / 30;
            float m = -1e30f;
            for (int i = r; i < Sn; i += 8) m = fmaxf(m, wm_s[i * 33 + j]);
            part[j * 8 + r] = m;
        }
        __syncthreads();
        if (t < Sn) {
            float m = part[t * 8];
            #pragma unroll
            for (int r = 1; r < 8; ++r) m = fmaxf(m, part[t * 8 + r]);
            colv[t] = m;
        }
        __syncthreads();
        if (t < 240) {
            int j = t % 30, r = t / 30;
            float m = colv[j], s = 0.f;
            for (int i = r; i < Sn; i += 8) {
                float e = __expf(wm_s[i * 33 + j] - m);
                wm_s[i * 33 + j] = e; s += e;
            }
            part[j * 8 + r] = s;
        }
        __syncthreads();
        if (t < Sn) {
            float s = 0.f;
            #pragma unroll
            for (int r = 0; r < 8; ++r) s += part[t * 8 + r];
            colv[t] = 1.f / s;
        }
        __syncthreads();
        for (int p = t; p < Sn * DHn; p += 256) vm[p] *= colv[p / DHn];
        __syncthreads();

        // ---- PV -> h2b[h*600 + i*20 + k] ----
        for (int p = t; p < Sn * DHn; p += 256) {
            int i = p / DHn, k = p - i * DHn;
            float acc = 0.f;
            #pragma unroll
            for (int j = 0; j < Sn; ++j) acc += wm_s[i * 33 + j] * vm[j * DHn + k];
            h2b[h * (Sn * DHn) + p] = acc;
        }
        __syncthreads();   // protect vm/qb for next head
    }

    // ---- fused additive pooling (h2b == [30 s][400 e] flat) ----
    int u = (t < AHn) ? t : AHn - 1;
    float acc[Sn];
    #pragma unroll
    for (int s = 0; s < Sn; ++s) acc[s] = 0.f;
    for (int k = 0; k < HDn; k += 4) {
        float4 wv = *(const float4*)&WVm[(size_t)u * HDn + k];
        #pragma unroll
        for (int s = 0; s < Sn; ++s) {
            float4 hv = *(const float4*)&h2b[s * HDn + k];
            acc[s] += hv.x*wv.x + hv.y*wv.y + hv.z*wv.z + hv.w*wv.w;
        }
    }
    float bias = bV[u];
    float wqv  = wq2[u];
    float mask = (t < AHn) ? 1.f : 0.f;
    int wid = t >> 6;
    #pragma unroll
    for (int s = 0; s < Sn; ++s) {
        float v = tanhf(acc[s] + bias) * wqv * mask;
        #pragma unroll
        for (int off = 32; off > 0; off >>= 1) v += __shfl_xor(v, off);
        if ((t & 63) == 0) wpart[wid * Sn + s] = v;
    }
    __syncthreads();
    if (t == 0) {
        float b2 = bq2[0];
        float sc[Sn], mx = -1e30f;
        for (int s = 0; s < Sn; ++s) {
            sc[s] = wpart[0 * Sn + s] + wpart[1 * Sn + s]
                  + wpart[2 * Sn + s] + wpart[3 * Sn + s] + b2;
            mx = fmaxf(mx, sc[s]);
        }
        float sum = 0.f;
        for (int s = 0; s < Sn; ++s) { float e = __expf(sc[s] - mx); psm[s] = e; sum += e; }
        float inv = 1.f / sum;
        for (int s = 0; s < Sn; ++s) psm[s] *= inv;
    }
    __syncthreads();
    for (int e = t; e < HDn; e += 256) {
        float z = 0.f;
        #pragma unroll
        for (int s = 0; s < Sn; ++s) z += psm[s] * h2b[s * HDn + e];
        out[(size_t)(b0 + bl) * HDn + e] = z;
    }
}

// ---------------------------------------------------------------------------
extern "C" void kernel_launch(void* const* d_in, const int* in_sizes, int n_in,
                              void* d_out, int out_size, void* d_ws, size_t ws_size,
                              hipStream_t stream)
{
    const int*   x   = (const int*)d_in[0];
    const float* emb = (const float*)d_in[1];
    const float* Wq  = (const float*)d_in[2];
    const float* bq  = (const float*)d_in[3];
    const float* Wv  = (const float*)d_in[4];
    const float* bv  = (const float*)d_in[5];
    const float* WVm = (const float*)d_in[6];
    const float* bV  = (const float*)d_in[7];
    const float* wq2 = (const float*)d_in[8];
    const float* bq2 = (const float*)d_in[9];
    float* outp = (float*)d_out;

    const size_t wbBytes = (size_t)NW * KP * 2;       // 4,096,000
    // per-b: cbf 19200 + xqb 360000 + xvb 24000 = 403,200
    size_t wrem = (ws_size > wbBytes) ? ws_size - wbBytes : 0;
    int CB = Bn;
    while (CB > 1 && (size_t)CB * 403200ull > wrem) CB >>= 1;

    char* ws = (char*)d_ws;
    unsigned short* Wb  = (unsigned short*)(ws);
    char* wsc = ws + wbBytes;
    unsigned short* cbf = (unsigned short*)(wsc);
    unsigned short* xqb = (unsigned short*)(wsc + (size_t)CB * 19200ull);
    unsigned short* xvb = (unsigned short*)(wsc + (size_t)CB * 379200ull);

    k_cast_w<<<dim3(2048), dim3(256), 0, stream>>>(Wq, Wv, Wb);

    for (int b0 = 0; b0 < Bn; b0 += CB) {
        int nloc = (b0 + CB <= Bn) ? CB : (Bn - b0);
        int Mloc = nloc * Sn;
        int mtiles = (Mloc + 127) / 128;
        int gc = (nloc * Sn * Dm + 255) / 256;
        if (gc > 2048) gc = 2048;
        k_c<<<dim3(gc), dim3(256), 0, stream>>>(x, emb, cbf, b0, nloc);
        k_xqm<<<dim3(50 * mtiles), dim3(256), 0, stream>>>(cbf, Wb, bq, bv,
                                                           xqb, xvb, Mloc, mtiles);
        k_attn<<<dim3(nloc), dim3(256), 0, stream>>>(cbf, xqb, xvb,
                                                     WVm, bV, wq2, bq2, outp, b0);
    }
}

// Round 16
// 355.882 us; speedup vs baseline: 1.3845x; 1.3845x over previous
//
#include <hip/hip_runtime.h>
#include <hip/hip_bf16.h>

#define Bn  512
#define Sn  30
#define Dm  300
#define Hn  20
#define DHn 20
#define AHn 200
#define HDn 400
#define EQn 6000
#define KP  320           // GEMM K padded to 10*32
#define NW  6400          // N = 6000 (Wq) + 400 (Wv) = 50*128 exactly
#define KB  328           // qb/kb LDS row stride (bf16); kT row stride too
#define CFS 304           // cf LDS row stride in k_kt

typedef __attribute__((ext_vector_type(8))) short short8;
typedef __attribute__((ext_vector_type(4))) short short4v;
typedef __attribute__((ext_vector_type(4))) float f32x4;

__device__ __forceinline__ unsigned short f2b(float v) {
    __hip_bfloat16 h = __float2bfloat16(v);
    return *(unsigned short*)&h;
}
__device__ __forceinline__ float b2f(unsigned short u) {
    union { unsigned int i; float f; } cv; cv.i = ((unsigned int)u) << 16; return cv.f;
}

// ---------------------------------------------------------------------------
// k_c: cbf[(bl*30+s)*320 + d] = bf16(emb[x][d] + PE(s,d)), K-pad zeroed
// ---------------------------------------------------------------------------
__global__ __launch_bounds__(256) void k_c(const int* __restrict__ x,
        const float* __restrict__ emb, unsigned short* __restrict__ cbf,
        int b0, int nloc)
{
    int n = nloc * Sn * Dm;
    for (int p = blockIdx.x * 256 + threadIdx.x; p < n; p += gridDim.x * 256) {
        int bl = p / (Sn * Dm);
        int r  = p - bl * (Sn * Dm);
        int s = r / Dm, d = r - s * Dm;
        int tok = x[(b0 + bl) * Sn + s];
        float dv = expf(-0.06140226914650789f * (float)(d >> 1));
        float ang = (float)s * dv;
        float val = emb[(size_t)tok * Dm + d] + ((d & 1) ? cosf(ang) : sinf(ang));
        cbf[(size_t)(bl * Sn + s) * KP + d] = f2b(val);
    }
    int npad = nloc * Sn * (KP - Dm);
    for (int p = blockIdx.x * 256 + threadIdx.x; p < npad; p += gridDim.x * 256) {
        int m = p / (KP - Dm), k = Dm + p % (KP - Dm);
        cbf[(size_t)m * KP + k] = 0;
    }
}

// ---------------------------------------------------------------------------
// k_kt: per bl, produce pre-transposed padded K tile:
//   kT[bl][j*KB + d] = bf16 K(d,j) = cbf_flat[bl][d*30+j]; rows>=30, d>=300 zero
// ---------------------------------------------------------------------------
__global__ __launch_bounds__(256) void k_kt(const unsigned short* __restrict__ cbf,
        unsigned short* __restrict__ kT)
{
    __shared__ __attribute__((aligned(16))) unsigned short cf[Sn * CFS];
    int bl = blockIdx.x, t = threadIdx.x;
    for (int q = t; q < 30 * 38; q += 256) {
        int i = q / 38, cc = q % 38, d0 = cc * 8;
        const unsigned short* src = &cbf[(size_t)(bl * Sn + i) * KP + d0];
        if (d0 + 8 <= Dm) *(short8*)&cf[i * CFS + d0] = *(const short8*)src;
        else              *(short4v*)&cf[i * CFS + d0] = *(const short4v*)src;
    }
    __syncthreads();
    // 32 rows x 41 short8-chunks = 1312
    for (int p = t; p < 1312; p += 256) {
        int j = p / 41, ch = p % 41, d0 = ch * 8;
        short8 v = {0, 0, 0, 0, 0, 0, 0, 0};
        if (j < Sn) {
            #pragma unroll
            for (int e = 0; e < 8; ++e) {
                int d = d0 + e;
                if (d < Dm) {
                    int f = d * Sn + j;
                    v[e] = (short)cf[(f / Dm) * CFS + (f % Dm)];
                }
            }
        }
        *(short8*)&kT[(size_t)bl * (32 * KB) + j * KB + d0] = v;
    }
}

// ---------------------------------------------------------------------------
// k_cast_w: Wb[NW][KP] = bf16([Wq; Wv]) zero-padded    (once per launch)
// ---------------------------------------------------------------------------
__global__ __launch_bounds__(256) void k_cast_w(const float* __restrict__ Wq,
        const float* __restrict__ Wv, unsigned short* __restrict__ Wb)
{
    for (int p = blockIdx.x * 256 + threadIdx.x; p < NW * KP; p += gridDim.x * 256) {
        int nq = p / KP, k = p - nq * KP;
        float v = 0.f;
        if (k < Dm)
            v = (nq < EQn) ? Wq[(size_t)nq * Dm + k]
                           : Wv[(size_t)(nq - EQn) * Dm + k];
        Wb[p] = f2b(v);
    }
}

// ---------------------------------------------------------------------------
// k_xqm: [xqb | xvb][m][n] = bf16(sum_k cbf[m][k]*Wb[n][k] + bias)
// (verified R14 kernel, unchanged)
// ---------------------------------------------------------------------------
__global__ __launch_bounds__(256) void k_xqm(const unsigned short* __restrict__ Ab,
        const unsigned short* __restrict__ Bb, const float* __restrict__ bq,
        const float* __restrict__ bv, unsigned short* __restrict__ xqb,
        unsigned short* __restrict__ xvb, int Mloc, int mtiles)
{
    __shared__ __attribute__((aligned(16))) char smem[36864];
    unsigned short (*As)[72] = (unsigned short (*)[72])smem;
    unsigned short (*Bs)[72] = (unsigned short (*)[72])(smem + 18432);
    unsigned short (*Cs)[136] = (unsigned short (*)[136])smem;

    int nwg = 50 * mtiles;
    int bid = blockIdx.x;
    int q8 = nwg >> 3, r8 = nwg & 7;
    int xcd = bid & 7, idx = bid >> 3;
    int wg = (xcd < r8 ? xcd * (q8 + 1) : r8 * (q8 + 1) + (xcd - r8) * q8) + idx;
    int bx = wg % 50, by = wg / 50;

    int t = threadIdx.x;
    int l = t & 63, w = t >> 6;
    int wm = w >> 1, wn = w & 1;
    int m0 = by * 128, n0 = bx * 128;
    int cl = l & 15, rh = l >> 4;

    f32x4 zero4 = {0.f, 0.f, 0.f, 0.f};
    f32x4 acc[4][4];
    #pragma unroll
    for (int a = 0; a < 4; ++a)
        #pragma unroll
        for (int bb = 0; bb < 4; ++bb) acc[a][bb] = zero4;

    for (int k0 = 0; k0 < KP; k0 += 64) {
        #pragma unroll
        for (int cc = 0; cc < 4; ++cc) {
            int qq = t + 256 * cc;
            int row = qq >> 3, kc = (qq & 7) * 8;
            int gm = m0 + row;
            short8 av = {0, 0, 0, 0, 0, 0, 0, 0};
            if (gm < Mloc) av = *(const short8*)&Ab[(size_t)gm * KP + k0 + kc];
            *(short8*)&As[row][kc] = av;
            short8 bvv = *(const short8*)&Bb[(size_t)(n0 + row) * KP + k0 + kc];
            *(short8*)&Bs[row][kc] = bvv;
        }
        __syncthreads();
        #pragma unroll
        for (int k2 = 0; k2 < 2; ++k2) {
            int kk = k2 * 32 + rh * 8;
            short8 af[4], bf[4];
            #pragma unroll
            for (int f = 0; f < 4; ++f) {
                af[f] = *(const short8*)&As[wm * 64 + f * 16 + cl][kk];
                bf[f] = *(const short8*)&Bs[wn * 64 + f * 16 + cl][kk];
            }
            #pragma unroll
            for (int mf = 0; mf < 4; ++mf)
                #pragma unroll
                for (int nf = 0; nf < 4; ++nf)
                    acc[mf][nf] = __builtin_amdgcn_mfma_f32_16x16x32_bf16(
                        af[mf], bf[nf], acc[mf][nf], 0, 0, 0);
        }
        __syncthreads();
    }

    #pragma unroll
    for (int nf = 0; nf < 4; ++nf) {
        int gn = n0 + wn * 64 + nf * 16 + cl;
        float bias = (gn < EQn) ? bq[gn] : bv[gn - EQn];
        #pragma unroll
        for (int mf = 0; mf < 4; ++mf) {
            int lrow = wm * 64 + mf * 16 + rh * 4;
            #pragma unroll
            for (int r = 0; r < 4; ++r)
                Cs[lrow + r][wn * 64 + nf * 16 + cl] = f2b(acc[mf][nf][r] + bias);
        }
    }
    __syncthreads();

    for (int ch = t; ch < 128 * 16; ch += 256) {
        int row = ch >> 4, colc = (ch & 15) * 8;
        int gm = m0 + row;
        if (gm >= Mloc) continue;
        short8 v = *(const short8*)&Cs[row][colc];
        int gn = n0 + colc;
        if (gn < EQn) *(short8*)&xqb[(size_t)gm * EQn + gn] = v;
        else          *(short8*)&xvb[(size_t)gm * HDn + (gn - EQn)] = v;
    }
}

// ---------------------------------------------------------------------------
// k_attn v4: per-(h,bl) block, 4 waves. All-vector staging from kT/xqb/xvb.
// Same-bl blocks clustered on one XCD when nloc%8==0.
// ---------------------------------------------------------------------------
__global__ __launch_bounds__(256) void k_attn(const unsigned short* __restrict__ kT,
        const unsigned short* __restrict__ xqb, const unsigned short* __restrict__ xvb,
        float* __restrict__ h2, int nloc)
{
    __shared__ __attribute__((aligned(16))) unsigned short qb[32 * KB];
    __shared__ __attribute__((aligned(16))) unsigned short kb[32 * KB];
    __shared__ float wm_s[32 * 33];
    __shared__ float vm[Sn * DHn];
    __shared__ float part[Sn * 8];
    __shared__ float colv[Sn];
    int t = threadIdx.x;

    int h, bl;
    {
        int bid = blockIdx.x;
        if ((nloc & 7) == 0) {
            int xcd = bid & 7, seq = bid >> 3;
            bl = xcd + 8 * (seq / Hn);
            h = seq % Hn;
        } else { h = bid % Hn; bl = bid / Hn; }
    }

    // zero Q pads: cols 300..319 rows 0..29; rows 30..31 whole
    for (int p = t; p < 600; p += 256) {
        int r = p / 20, cc = Dm + p % 20;
        qb[r * KB + cc] = 0;
    }
    for (int p = t; p < 2 * KB; p += 256) qb[30 * KB + p] = 0;

    // K: straight vector copy of pre-transposed tile (pads baked in)
    for (int p = t; p < 1312; p += 256)
        *(short8*)&kb[p * 8] = *(const short8*)&kT[(size_t)bl * (32 * KB) + p * 8];

    // Q: head slice is 9000 contiguous bf16; rows of 300 = 37*8 + 4
    const unsigned short* qsrc = xqb + (size_t)bl * (Sn * EQn) + (size_t)h * (Sn * Dm);
    for (int q = t; q < 30 * 38; q += 256) {
        int i = q / 38, cc = q % 38, d0 = cc * 8;
        const unsigned short* src = &qsrc[i * Dm + d0];
        if (d0 + 8 <= Dm) *(short8*)&qb[i * KB + d0] = *(const short8*)src;
        else              *(short4v*)&qb[i * KB + d0] = *(const short4v*)src;
    }
    if (t < 75) {
        short8 v = *(const short8*)&xvb[(size_t)bl * (Sn * HDn) + h * (Sn * DHn) + t * 8];
        #pragma unroll
        for (int e = 0; e < 8; ++e) vm[t * 8 + e] = b2f((unsigned short)v[e]);
    }
    __syncthreads();

    // scores via MFMA: wave w -> 16x16 tile (w>>1, w&1)
    {
        int l = t & 63, w = t >> 6;
        int wmt = w >> 1, wnt = w & 1;
        int cl = l & 15, rh = l >> 4;
        f32x4 acc = {0.f, 0.f, 0.f, 0.f};
        #pragma unroll
        for (int ks = 0; ks < 10; ++ks) {
            short8 a = *(const short8*)&qb[(wmt * 16 + cl) * KB + ks * 32 + rh * 8];
            short8 b = *(const short8*)&kb[(wnt * 16 + cl) * KB + ks * 32 + rh * 8];
            acc = __builtin_amdgcn_mfma_f32_16x16x32_bf16(a, b, acc, 0, 0, 0);
        }
        #pragma unroll
        for (int r = 0; r < 4; ++r) {
            int i = wmt * 16 + rh * 4 + r, j = wnt * 16 + cl;
            if (i < Sn && j < Sn) wm_s[i * 33 + j] = acc[r];
        }
    }
    __syncthreads();

    // softmax over query dim i (per column j)
    if (t < 240) {
        int j = t % 30, r = t / 30;
        float m = -1e30f;
        for (int i = r; i < Sn; i += 8) m = fmaxf(m, wm_s[i * 33 + j]);
        part[j * 8 + r] = m;
    }
    __syncthreads();
    if (t < Sn) {
        float m = part[t * 8];
        #pragma unroll
        for (int r = 1; r < 8; ++r) m = fmaxf(m, part[t * 8 + r]);
        colv[t] = m;
    }
    __syncthreads();
    if (t < 240) {
        int j = t % 30, r = t / 30;
        float m = colv[j], s = 0.f;
        for (int i = r; i < Sn; i += 8) {
            float e = __expf(wm_s[i * 33 + j] - m);
            wm_s[i * 33 + j] = e; s += e;
        }
        part[j * 8 + r] = s;
    }
    __syncthreads();
    if (t < Sn) {
        float s = 0.f;
        #pragma unroll
        for (int r = 0; r < 8; ++r) s += part[t * 8 + r];
        colv[t] = 1.f / s;
    }
    __syncthreads();
    for (int p = t; p < Sn * DHn; p += 256) vm[p] *= colv[p / DHn];
    __syncthreads();

    for (int p = t; p < Sn * DHn; p += 256) {
        int i = p / DHn, k = p - i * DHn;
        float acc = 0.f;
        #pragma unroll
        for (int j = 0; j < Sn; ++j) acc += wm_s[i * 33 + j] * vm[j * DHn + k];
        h2[(size_t)bl * (Sn * HDn) + (size_t)h * (Sn * DHn) + p] = acc;
    }
}

// ---------------------------------------------------------------------------
// k_pool: additive pooling per bl -> out[(b0+bl)][400]  (f32 out)
// ---------------------------------------------------------------------------
__global__ __launch_bounds__(256) void k_pool(const float* __restrict__ h2,
        const float* __restrict__ WVm, const float* __restrict__ bV,
        const float* __restrict__ wq2, const float* __restrict__ bq2,
        float* __restrict__ out, int b0)
{
    __shared__ __attribute__((aligned(16))) float hb[Sn * HDn];
    __shared__ float wpart[4][Sn];
    __shared__ float psm[Sn];
    int bl = blockIdx.x, t = threadIdx.x;
    for (int i = t; i < Sn * HDn; i += 256) hb[i] = h2[(size_t)bl * (Sn * HDn) + i];
    __syncthreads();

    int u = (t < AHn) ? t : AHn - 1;
    float acc[Sn];
    #pragma unroll
    for (int s = 0; s < Sn; ++s) acc[s] = 0.f;
    for (int k = 0; k < HDn; k += 4) {
        float4 wv = *(const float4*)&WVm[(size_t)u * HDn + k];
        #pragma unroll
        for (int s = 0; s < Sn; ++s) {
            float4 hv = *(const float4*)&hb[s * HDn + k];
            acc[s] += hv.x*wv.x + hv.y*wv.y + hv.z*wv.z + hv.w*wv.w;
        }
    }
    float bias = bV[u];
    float wqv  = wq2[u];
    float mask = (t < AHn) ? 1.f : 0.f;
    int wid = t >> 6;
    #pragma unroll
    for (int s = 0; s < Sn; ++s) {
        float v = tanhf(acc[s] + bias) * wqv * mask;
        #pragma unroll
        for (int off = 32; off > 0; off >>= 1) v += __shfl_xor(v, off);
        if ((t & 63) == 0) wpart[wid][s] = v;
    }
    __syncthreads();
    if (t == 0) {
        float b2 = bq2[0];
        float sc[Sn], mx = -1e30f;
        for (int s = 0; s < Sn; ++s) {
            sc[s] = wpart[0][s] + wpart[1][s] + wpart[2][s] + wpart[3][s] + b2;
            mx = fmaxf(mx, sc[s]);
        }
        float sum = 0.f;
        for (int s = 0; s < Sn; ++s) { float e = __expf(sc[s] - mx); psm[s] = e; sum += e; }
        float inv = 1.f / sum;
        for (int s = 0; s < Sn; ++s) psm[s] *= inv;
    }
    __syncthreads();
    for (int e = t; e < HDn; e += 256) {
        float z = 0.f;
        #pragma unroll
        for (int s = 0; s < Sn; ++s) z += psm[s] * hb[s * HDn + e];
        out[(size_t)(b0 + bl) * HDn + e] = z;
    }
}

// ---------------------------------------------------------------------------
extern "C" void kernel_launch(void* const* d_in, const int* in_sizes, int n_in,
                              void* d_out, int out_size, void* d_ws, size_t ws_size,
                              hipStream_t stream)
{
    const int*   x   = (const int*)d_in[0];
    const float* emb = (const float*)d_in[1];
    const float* Wq  = (const float*)d_in[2];
    const float* bq  = (const float*)d_in[3];
    const float* Wv  = (const float*)d_in[4];
    const float* bv  = (const float*)d_in[5];
    const float* WVm = (const float*)d_in[6];
    const float* bV  = (const float*)d_in[7];
    const float* wq2 = (const float*)d_in[8];
    const float* bq2 = (const float*)d_in[9];
    float* outp = (float*)d_out;

    const size_t wbBytes = (size_t)NW * KP * 2;       // 4,096,000
    // per-b: cbf 19200 + xqb 360000 + xvb 24000 + kT 20992 + h2 48000 = 472,192
    size_t wrem = (ws_size > wbBytes) ? ws_size - wbBytes : 0;
    int CB = Bn;
    while (CB > 1 && (size_t)CB * 472192ull > wrem) CB >>= 1;

    char* ws = (char*)d_ws;
    unsigned short* Wb  = (unsigned short*)(ws);
    char* wsc = ws + wbBytes;
    unsigned short* cbf = (unsigned short*)(wsc);
    unsigned short* xqb = (unsigned short*)(wsc + (size_t)CB * 19200ull);
    unsigned short* xvb = (unsigned short*)(wsc + (size_t)CB * 379200ull);
    unsigned short* kT  = (unsigned short*)(wsc + (size_t)CB * 403200ull);
    float*          h2  = (float*)(wsc + (size_t)CB * 424192ull);

    k_cast_w<<<dim3(2048), dim3(256), 0, stream>>>(Wq, Wv, Wb);

    for (int b0 = 0; b0 < Bn; b0 += CB) {
        int nloc = (b0 + CB <= Bn) ? CB : (Bn - b0);
        int Mloc = nloc * Sn;
        int mtiles = (Mloc + 127) / 128;
        int gc = (nloc * Sn * Dm + 255) / 256;
        if (gc > 2048) gc = 2048;
        k_c<<<dim3(gc), dim3(256), 0, stream>>>(x, emb, cbf, b0, nloc);
        k_kt<<<dim3(nloc), dim3(256), 0, stream>>>(cbf, kT);
        k_xqm<<<dim3(50 * mtiles), dim3(256), 0, stream>>>(cbf, Wb, bq, bv,
                                                           xqb, xvb, Mloc, mtiles);
        k_attn<<<dim3(Hn * nloc), dim3(256), 0, stream>>>(kT, xqb, xvb, h2, nloc);
        k_pool<<<dim3(nloc), dim3(256), 0, stream>>>(h2, WVm, bV, wq2, bq2, outp, b0);
    }
}

// Round 17
// 280.480 us; speedup vs baseline: 1.7567x; 1.2688x over previous
//
#include <hip/hip_runtime.h>
#include <hip/hip_bf16.h>

#define Bn  512
#define Sn  30
#define Dm  300
#define Hn  20
#define DHn 20
#define AHn 200
#define HDn 400
#define EQn 6000
#define KP  320           // GEMM K padded to 10*32
#define NW  6400          // N = 6000 (Wq) + 400 (Wv) = 50*128 exactly
#define KB  328           // kb/kT row stride (bf16)
#define CFS 304           // cf LDS row stride in k_kt

typedef __attribute__((ext_vector_type(8))) short short8;
typedef __attribute__((ext_vector_type(4))) short short4v;
typedef __attribute__((ext_vector_type(4))) float f32x4;

__device__ __forceinline__ unsigned short f2b(float v) {
    __hip_bfloat16 h = __float2bfloat16(v);
    return *(unsigned short*)&h;
}
__device__ __forceinline__ float b2f(unsigned short u) {
    union { unsigned int i; float f; } cv; cv.i = ((unsigned int)u) << 16; return cv.f;
}

// ---------------------------------------------------------------------------
// k_c: cbf[(bl*30+s)*320 + d] = bf16(emb[x][d] + PE(s,d)), K-pad zeroed
// ---------------------------------------------------------------------------
__global__ __launch_bounds__(256) void k_c(const int* __restrict__ x,
        const float* __restrict__ emb, unsigned short* __restrict__ cbf,
        int b0, int nloc)
{
    int n = nloc * Sn * Dm;
    for (int p = blockIdx.x * 256 + threadIdx.x; p < n; p += gridDim.x * 256) {
        int bl = p / (Sn * Dm);
        int r  = p - bl * (Sn * Dm);
        int s = r / Dm, d = r - s * Dm;
        int tok = x[(b0 + bl) * Sn + s];
        float dv = expf(-0.06140226914650789f * (float)(d >> 1));
        float ang = (float)s * dv;
        float val = emb[(size_t)tok * Dm + d] + ((d & 1) ? cosf(ang) : sinf(ang));
        cbf[(size_t)(bl * Sn + s) * KP + d] = f2b(val);
    }
    int npad = nloc * Sn * (KP - Dm);
    for (int p = blockIdx.x * 256 + threadIdx.x; p < npad; p += gridDim.x * 256) {
        int m = p / (KP - Dm), k = Dm + p % (KP - Dm);
        cbf[(size_t)m * KP + k] = 0;
    }
}

// ---------------------------------------------------------------------------
// k_kt: per bl, pre-transposed padded K tile: kT[bl][j*KB+d] = cbf_flat[d*30+j]
// ---------------------------------------------------------------------------
__global__ __launch_bounds__(256) void k_kt(const unsigned short* __restrict__ cbf,
        unsigned short* __restrict__ kT)
{
    __shared__ __attribute__((aligned(16))) unsigned short cf[Sn * CFS];
    int bl = blockIdx.x, t = threadIdx.x;
    for (int q = t; q < 30 * 38; q += 256) {
        int i = q / 38, cc = q % 38, d0 = cc * 8;
        const unsigned short* src = &cbf[(size_t)(bl * Sn + i) * KP + d0];
        if (d0 + 8 <= Dm) *(short8*)&cf[i * CFS + d0] = *(const short8*)src;
        else              *(short4v*)&cf[i * CFS + d0] = *(const short4v*)src;
    }
    __syncthreads();
    for (int p = t; p < 1312; p += 256) {
        int j = p / 41, ch = p % 41, d0 = ch * 8;
        short8 v = {0, 0, 0, 0, 0, 0, 0, 0};
        if (j < Sn) {
            #pragma unroll
            for (int e = 0; e < 8; ++e) {
                int d = d0 + e;
                if (d < Dm) {
                    int f = d * Sn + j;
                    v[e] = (short)cf[(f / Dm) * CFS + (f % Dm)];
                }
            }
        }
        *(short8*)&kT[(size_t)bl * (32 * KB) + j * KB + d0] = v;
    }
}

// ---------------------------------------------------------------------------
// k_cast_w: Wb[NW][KP] = bf16([Wq; Wv]) zero-padded    (once per launch)
// ---------------------------------------------------------------------------
__global__ __launch_bounds__(256) void k_cast_w(const float* __restrict__ Wq,
        const float* __restrict__ Wv, unsigned short* __restrict__ Wb)
{
    for (int p = blockIdx.x * 256 + threadIdx.x; p < NW * KP; p += gridDim.x * 256) {
        int nq = p / KP, k = p - nq * KP;
        float v = 0.f;
        if (k < Dm)
            v = (nq < EQn) ? Wq[(size_t)nq * Dm + k]
                           : Wv[(size_t)(nq - EQn) * Dm + k];
        Wb[p] = f2b(v);
    }
}

// ---------------------------------------------------------------------------
// k_xqm: [xqb | xvb][m][n] = bf16(sum_k cbf[m][k]*Wb[n][k] + bias)
// (verified R14 kernel, unchanged)
// ---------------------------------------------------------------------------
__global__ __launch_bounds__(256) void k_xqm(const unsigned short* __restrict__ Ab,
        const unsigned short* __restrict__ Bb, const float* __restrict__ bq,
        const float* __restrict__ bv, unsigned short* __restrict__ xqb,
        unsigned short* __restrict__ xvb, int Mloc, int mtiles)
{
    __shared__ __attribute__((aligned(16))) char smem[36864];
    unsigned short (*As)[72] = (unsigned short (*)[72])smem;
    unsigned short (*Bs)[72] = (unsigned short (*)[72])(smem + 18432);
    unsigned short (*Cs)[136] = (unsigned short (*)[136])smem;

    int nwg = 50 * mtiles;
    int bid = blockIdx.x;
    int q8 = nwg >> 3, r8 = nwg & 7;
    int xcd = bid & 7, idx = bid >> 3;
    int wg = (xcd < r8 ? xcd * (q8 + 1) : r8 * (q8 + 1) + (xcd - r8) * q8) + idx;
    int bx = wg % 50, by = wg / 50;

    int t = threadIdx.x;
    int l = t & 63, w = t >> 6;
    int wm = w >> 1, wn = w & 1;
    int m0 = by * 128, n0 = bx * 128;
    int cl = l & 15, rh = l >> 4;

    f32x4 zero4 = {0.f, 0.f, 0.f, 0.f};
    f32x4 acc[4][4];
    #pragma unroll
    for (int a = 0; a < 4; ++a)
        #pragma unroll
        for (int bb = 0; bb < 4; ++bb) acc[a][bb] = zero4;

    for (int k0 = 0; k0 < KP; k0 += 64) {
        #pragma unroll
        for (int cc = 0; cc < 4; ++cc) {
            int qq = t + 256 * cc;
            int row = qq >> 3, kc = (qq & 7) * 8;
            int gm = m0 + row;
            short8 av = {0, 0, 0, 0, 0, 0, 0, 0};
            if (gm < Mloc) av = *(const short8*)&Ab[(size_t)gm * KP + k0 + kc];
            *(short8*)&As[row][kc] = av;
            short8 bvv = *(const short8*)&Bb[(size_t)(n0 + row) * KP + k0 + kc];
            *(short8*)&Bs[row][kc] = bvv;
        }
        __syncthreads();
        #pragma unroll
        for (int k2 = 0; k2 < 2; ++k2) {
            int kk = k2 * 32 + rh * 8;
            short8 af[4], bf[4];
            #pragma unroll
            for (int f = 0; f < 4; ++f) {
                af[f] = *(const short8*)&As[wm * 64 + f * 16 + cl][kk];
                bf[f] = *(const short8*)&Bs[wn * 64 + f * 16 + cl][kk];
            }
            #pragma unroll
            for (int mf = 0; mf < 4; ++mf)
                #pragma unroll
                for (int nf = 0; nf < 4; ++nf)
                    acc[mf][nf] = __builtin_amdgcn_mfma_f32_16x16x32_bf16(
                        af[mf], bf[nf], acc[mf][nf], 0, 0, 0);
        }
        __syncthreads();
    }

    #pragma unroll
    for (int nf = 0; nf < 4; ++nf) {
        int gn = n0 + wn * 64 + nf * 16 + cl;
        float bias = (gn < EQn) ? bq[gn] : bv[gn - EQn];
        #pragma unroll
        for (int mf = 0; mf < 4; ++mf) {
            int lrow = wm * 64 + mf * 16 + rh * 4;
            #pragma unroll
            for (int r = 0; r < 4; ++r)
                Cs[lrow + r][wn * 64 + nf * 16 + cl] = f2b(acc[mf][nf][r] + bias);
        }
    }
    __syncthreads();

    for (int ch = t; ch < 128 * 16; ch += 256) {
        int row = ch >> 4, colc = (ch & 15) * 8;
        int gm = m0 + row;
        if (gm >= Mloc) continue;
        short8 v = *(const short8*)&Cs[row][colc];
        int gn = n0 + colc;
        if (gn < EQn) *(short8*)&xqb[(size_t)gm * EQn + gn] = v;
        else          *(short8*)&xvb[(size_t)gm * HDn + (gn - EQn)] = v;
    }
}

// ---------------------------------------------------------------------------
// k_attn v5: WAVE = HEAD. Block = (bl, head-group of 4). 5 blocks per bl.
// K in LDS (1 barrier); Q global->VGPR fragments; register softmax via shfl;
// per-wave LDS P + V; scalar PV. No per-head barriers.
// ---------------------------------------------------------------------------
__global__ __launch_bounds__(256) void k_attn(const unsigned short* __restrict__ kT,
        const unsigned short* __restrict__ xqb, const unsigned short* __restrict__ xvb,
        float* __restrict__ h2, int nwg)
{
    __shared__ __attribute__((aligned(16))) unsigned short kb[32 * KB]; // 20992 B
    __shared__ float wmw[4][32 * 33];                                   // 16896 B
    __shared__ float vmw[4][Sn * DHn];                                  //  9600 B

    int t = threadIdx.x, l = t & 63, w = t >> 6;
    int cl = l & 15, rh = l >> 4;

    // bijective XCD swizzle: 5 same-bl blocks land on one XCD
    int bid = blockIdx.x;
    int q8 = nwg >> 3, r8 = nwg & 7;
    int xcd = bid & 7, idx = bid >> 3;
    int wg = (xcd < r8 ? xcd * (q8 + 1) : r8 * (q8 + 1) + (xcd - r8) * q8) + idx;
    int bl = wg / 5, hg = wg % 5;
    int h = hg * 4 + w;

    // K: cooperative copy of pre-transposed zero-padded tile
    for (int p = t; p < 1312; p += 256)
        *(short8*)&kb[p * 8] = *(const short8*)&kT[(size_t)bl * (32 * KB) + p * 8];

    // V: per-wave stage (600 bf16 -> f32)
    const unsigned short* vsrc = xvb + (size_t)bl * (Sn * HDn) + h * (Sn * DHn);
    for (int ch = l; ch < 75; ch += 64) {
        short8 v = *(const short8*)&vsrc[ch * 8];
        #pragma unroll
        for (int e = 0; e < 8; ++e) vmw[w][ch * 8 + e] = b2f((unsigned short)v[e]);
    }

    // Q: direct global->VGPR fragments (head slice = 9000 contiguous bf16)
    const unsigned short* qsrc = xqb + (size_t)bl * (Sn * EQn) + (size_t)h * (Sn * Dm);
    short8 aq[2][10];
    #pragma unroll
    for (int ti = 0; ti < 2; ++ti) {
        int row = ti * 16 + cl; if (row > 29) row = 29;   // clamp; rows 30/31 discarded
        const unsigned short* qrow = qsrc + row * Dm;
        #pragma unroll
        for (int ks = 0; ks < 9; ++ks)
            aq[ti][ks] = *(const short8*)&qrow[ks * 32 + rh * 8];
        // ks=9 covers d 288..319; valid d < 300
        short8 a9 = {0, 0, 0, 0, 0, 0, 0, 0};
        if (rh == 0) a9 = *(const short8*)&qrow[288];
        else if (rh == 1) {
            short4v lo = *(const short4v*)&qrow[296];
            a9[0] = lo.x; a9[1] = lo.y; a9[2] = lo.z; a9[3] = lo.w;
        }
        aq[ti][9] = a9;
    }
    __syncthreads();   // kb ready (the only block barrier)

    // scores: 2x2 tiles of 16x16, K-loop of 10
    f32x4 zero4 = {0.f, 0.f, 0.f, 0.f};
    f32x4 acc[2][2] = {{zero4, zero4}, {zero4, zero4}};
    #pragma unroll
    for (int ks = 0; ks < 10; ++ks) {
        short8 b0 = *(const short8*)&kb[cl * KB + ks * 32 + rh * 8];
        short8 b1 = *(const short8*)&kb[(16 + cl) * KB + ks * 32 + rh * 8];
        #pragma unroll
        for (int ti = 0; ti < 2; ++ti) {
            acc[ti][0] = __builtin_amdgcn_mfma_f32_16x16x32_bf16(aq[ti][ks], b0, acc[ti][0], 0, 0, 0);
            acc[ti][1] = __builtin_amdgcn_mfma_f32_16x16x32_bf16(aq[ti][ks], b1, acc[ti][1], 0, 0, 0);
        }
    }

    // register softmax over query dim i (per column j); lane owns cols j0=cl, j1=16+cl
    float m0 = -1e30f, m1 = -1e30f;
    #pragma unroll
    for (int ti = 0; ti < 2; ++ti)
        #pragma unroll
        for (int r = 0; r < 4; ++r) {
            int i = ti * 16 + rh * 4 + r;
            if (i < Sn) { m0 = fmaxf(m0, acc[ti][0][r]); m1 = fmaxf(m1, acc[ti][1][r]); }
        }
    m0 = fmaxf(m0, __shfl_xor(m0, 16)); m0 = fmaxf(m0, __shfl_xor(m0, 32));
    m1 = fmaxf(m1, __shfl_xor(m1, 16)); m1 = fmaxf(m1, __shfl_xor(m1, 32));

    float e0[2][4], e1[2][4], s0 = 0.f, s1 = 0.f;
    #pragma unroll
    for (int ti = 0; ti < 2; ++ti)
        #pragma unroll
        for (int r = 0; r < 4; ++r) {
            int i = ti * 16 + rh * 4 + r;
            float v0 = 0.f, v1 = 0.f;
            if (i < Sn) {
                v0 = __expf(acc[ti][0][r] - m0);
                v1 = __expf(acc[ti][1][r] - m1);
            }
            e0[ti][r] = v0; e1[ti][r] = v1;
            s0 += v0; s1 += v1;
        }
    s0 += __shfl_xor(s0, 16); s0 += __shfl_xor(s0, 32);
    s1 += __shfl_xor(s1, 16); s1 += __shfl_xor(s1, 32);
    float inv0 = 1.f / s0, inv1 = 1.f / s1;

    // write normalized P to per-wave LDS (wave-local; no barrier)
    #pragma unroll
    for (int ti = 0; ti < 2; ++ti)
        #pragma unroll
        for (int r = 0; r < 4; ++r) {
            int i = ti * 16 + rh * 4 + r;
            if (i < Sn) {
                wmw[w][i * 33 + cl] = e0[ti][r] * inv0;
                if (cl < 14) wmw[w][i * 33 + 16 + cl] = e1[ti][r] * inv1;
            }
        }

    // PV per wave: hout[i][k] = sum_j P[i][j] * V[j][k]
    for (int p = l; p < Sn * DHn; p += 64) {
        int i = p / DHn, k = p - i * DHn;
        float a = 0.f;
        #pragma unroll
        for (int j = 0; j < Sn; ++j) a += wmw[w][i * 33 + j] * vmw[w][j * DHn + k];
        h2[(size_t)bl * (Sn * HDn) + h * (Sn * DHn) + p] = a;
    }
}

// ---------------------------------------------------------------------------
// k_pool: additive pooling per bl -> out[(b0+bl)][400]  (f32 out)
// ---------------------------------------------------------------------------
__global__ __launch_bounds__(256) void k_pool(const float* __restrict__ h2,
        const float* __restrict__ WVm, const float* __restrict__ bV,
        const float* __restrict__ wq2, const float* __restrict__ bq2,
        float* __restrict__ out, int b0)
{
    __shared__ __attribute__((aligned(16))) float hb[Sn * HDn];
    __shared__ float wpart[4][Sn];
    __shared__ float psm[Sn];
    int bl = blockIdx.x, t = threadIdx.x;
    for (int i = t; i < Sn * HDn; i += 256) hb[i] = h2[(size_t)bl * (Sn * HDn) + i];
    __syncthreads();

    int u = (t < AHn) ? t : AHn - 1;
    float acc[Sn];
    #pragma unroll
    for (int s = 0; s < Sn; ++s) acc[s] = 0.f;
    for (int k = 0; k < HDn; k += 4) {
        float4 wv = *(const float4*)&WVm[(size_t)u * HDn + k];
        #pragma unroll
        for (int s = 0; s < Sn; ++s) {
            float4 hv = *(const float4*)&hb[s * HDn + k];
            acc[s] += hv.x*wv.x + hv.y*wv.y + hv.z*wv.z + hv.w*wv.w;
        }
    }
    float bias = bV[u];
    float wqv  = wq2[u];
    float mask = (t < AHn) ? 1.f : 0.f;
    int wid = t >> 6;
    #pragma unroll
    for (int s = 0; s < Sn; ++s) {
        float v = tanhf(acc[s] + bias) * wqv * mask;
        #pragma unroll
        for (int off = 32; off > 0; off >>= 1) v += __shfl_xor(v, off);
        if ((t & 63) == 0) wpart[wid][s] = v;
    }
    __syncthreads();
    if (t == 0) {
        float b2 = bq2[0];
        float sc[Sn], mx = -1e30f;
        for (int s = 0; s < Sn; ++s) {
            sc[s] = wpart[0][s] + wpart[1][s] + wpart[2][s] + wpart[3][s] + b2;
            mx = fmaxf(mx, sc[s]);
        }
        float sum = 0.f;
        for (int s = 0; s < Sn; ++s) { float e = __expf(sc[s] - mx); psm[s] = e; sum += e; }
        float inv = 1.f / sum;
        for (int s = 0; s < Sn; ++s) psm[s] *= inv;
    }
    __syncthreads();
    for (int e = t; e < HDn; e += 256) {
        float z = 0.f;
        #pragma unroll
        for (int s = 0; s < Sn; ++s) z += psm[s] * hb[s * HDn + e];
        out[(size_t)(b0 + bl) * HDn + e] = z;
    }
}

// ---------------------------------------------------------------------------
extern "C" void kernel_launch(void* const* d_in, const int* in_sizes, int n_in,
                              void* d_out, int out_size, void* d_ws, size_t ws_size,
                              hipStream_t stream)
{
    const int*   x   = (const int*)d_in[0];
    const float* emb = (const float*)d_in[1];
    const float* Wq  = (const float*)d_in[2];
    const float* bq  = (const float*)d_in[3];
    const float* Wv  = (const float*)d_in[4];
    const float* bv  = (const float*)d_in[5];
    const float* WVm = (const float*)d_in[6];
    const float* bV  = (const float*)d_in[7];
    const float* wq2 = (const float*)d_in[8];
    const float* bq2 = (const float*)d_in[9];
    float* outp = (float*)d_out;

    const size_t wbBytes = (size_t)NW * KP * 2;       // 4,096,000
    // per-b: cbf 19200 + xqb 360000 + xvb 24000 + kT 20992 + h2 48000 = 472,192
    size_t wrem = (ws_size > wbBytes) ? ws_size - wbBytes : 0;
    int CB = Bn;
    while (CB > 1 && (size_t)CB * 472192ull > wrem) CB >>= 1;

    char* ws = (char*)d_ws;
    unsigned short* Wb  = (unsigned short*)(ws);
    char* wsc = ws + wbBytes;
    unsigned short* cbf = (unsigned short*)(wsc);
    unsigned short* xqb = (unsigned short*)(wsc + (size_t)CB * 19200ull);
    unsigned short* xvb = (unsigned short*)(wsc + (size_t)CB * 379200ull);
    unsigned short* kT  = (unsigned short*)(wsc + (size_t)CB * 403200ull);
    float*          h2  = (float*)(wsc + (size_t)CB * 424192ull);

    k_cast_w<<<dim3(2048), dim3(256), 0, stream>>>(Wq, Wv, Wb);

    for (int b0 = 0; b0 < Bn; b0 += CB) {
        int nloc = (b0 + CB <= Bn) ? CB : (Bn - b0);
        int Mloc = nloc * Sn;
        int mtiles = (Mloc + 127) / 128;
        int gc = (nloc * Sn * Dm + 255) / 256;
        if (gc > 2048) gc = 2048;
        k_c<<<dim3(gc), dim3(256), 0, stream>>>(x, emb, cbf, b0, nloc);
        k_kt<<<dim3(nloc), dim3(256), 0, stream>>>(cbf, kT);
        k_xqm<<<dim3(50 * mtiles), dim3(256), 0, stream>>>(cbf, Wb, bq, bv,
                                                           xqb, xvb, Mloc, mtiles);
        int nwg = nloc * 5;
        k_attn<<<dim3(nwg), dim3(256), 0, stream>>>(kT, xqb, xvb, h2, nwg);
        k_pool<<<dim3(nloc), dim3(256), 0, stream>>>(h2, WVm, bV, wq2, bq2, outp, b0);
    }
}